// Round 9
// baseline (2934.846 us; speedup 1.0000x reference)
//
#include <hip/hip_runtime.h>
#include <hip/hip_fp16.h>

#define DIMM 128
#define LEAKY_S 0.01f
#define EPS_BN 1e-5f
#define NSLICE 8            // 8 col-slices x 16 cols; slice = blockIdx % 8 (XCD round-robin)

typedef _Float16 half8 __attribute__((ext_vector_type(8)));
typedef float f32x4 __attribute__((ext_vector_type(4)));
typedef unsigned int uivec4 __attribute__((ext_vector_type(4)));   // for nontemporal 16B stores

// ---------------------------------------------------------------------------
// Graph preprocessing: degree -> rowptr (scan over deg+1, self-loop slot) ->
// dinv + self entry -> CSR fill (col-only, 4B)
// ---------------------------------------------------------------------------

__global__ __launch_bounds__(256) void k_deg(const int* __restrict__ dst, int* __restrict__ deg, int E, int N) {
    int i = blockIdx.x * 256 + threadIdx.x;
    if (i < E) {
        int d = dst[i];
        if ((unsigned)d < (unsigned)N) atomicAdd(&deg[d], 1);
    }
}

__global__ __launch_bounds__(256) void k_scanA(const int* __restrict__ deg, int* __restrict__ bsum, int n) {
    __shared__ int ws[4];
    int tid = threadIdx.x, lane = tid & 63, wid = tid >> 6;
    int base = blockIdx.x * 1024;
    int s = 0;
    #pragma unroll
    for (int j = 0; j < 4; ++j) {
        int i = base + j * 256 + tid;
        if (i < n) s += deg[i] + 1;          // +1 self-loop slot
    }
    #pragma unroll
    for (int off = 32; off > 0; off >>= 1) s += __shfl_down(s, (unsigned)off, 64);
    if (lane == 0) ws[wid] = s;
    __syncthreads();
    if (tid == 0) bsum[blockIdx.x] = ws[0] + ws[1] + ws[2] + ws[3];
}

__global__ __launch_bounds__(64) void k_scanB(const int* __restrict__ bsum, int* __restrict__ bofs,
                                              int* __restrict__ rowptr, int nb, int n) {
    if (threadIdx.x == 0) {
        int run = 0;
        for (int j = 0; j < nb; ++j) { bofs[j] = run; run += bsum[j]; }
        rowptr[n] = run;
    }
}

__global__ __launch_bounds__(1024) void k_scanC(const int* __restrict__ deg, const int* __restrict__ bofs,
                                                int* __restrict__ rowptr, int n) {
    __shared__ int wsum[16];
    int tid = threadIdx.x, lane = tid & 63, wid = tid >> 6;
    int i = blockIdx.x * 1024 + tid;
    int v = (i < n) ? deg[i] + 1 : 0;        // +1 self-loop slot
    int s = v;
    #pragma unroll
    for (int off = 1; off < 64; off <<= 1) {
        int t = __shfl_up(s, (unsigned)off, 64);
        if (lane >= off) s += t;
    }
    if (lane == 63) wsum[wid] = s;
    __syncthreads();
    if (wid == 0 && lane < 16) {
        int ws = wsum[lane];
        #pragma unroll
        for (int off = 1; off < 16; off <<= 1) {
            int t = __shfl_up(ws, (unsigned)off, 64);
            if (lane >= off) ws += t;
        }
        wsum[lane] = ws;
    }
    __syncthreads();
    int woff = wid ? wsum[wid - 1] : 0;
    if (i < n) rowptr[i] = bofs[blockIdx.x] + woff + (s - v);
}

// dinv + self-loop entry at slot rowptr[i] (col = i -> weight dinv[i]^2 automatic)
__global__ __launch_bounds__(256) void k_dinvself(const int* __restrict__ deg, const int* __restrict__ rowptr,
                                                  float* __restrict__ dinv, int* __restrict__ csrcol, int N) {
    int i = blockIdx.x * 256 + threadIdx.x;
    if (i < N) {
        dinv[i] = rsqrtf((float)(deg[i] + 1));
        csrcol[rowptr[i]] = i;
    }
}

// CSR fill: col only (4B). Slot 0 of each row reserved for the self-loop.
__global__ __launch_bounds__(256) void k_fill(const int* __restrict__ src, const int* __restrict__ dst,
                                              const int* __restrict__ rowptr, int* __restrict__ cursor,
                                              int* __restrict__ csrcol, int E, int N) {
    int i = blockIdx.x * 256 + threadIdx.x;
    if (i < E) {
        int d = dst[i], s = src[i];
        if ((unsigned)d < (unsigned)N && (unsigned)s < (unsigned)N) {
            int pos = 1 + atomicAdd(&cursor[d], 1);
            csrcol[rowptr[d] + pos] = s;
        }
    }
}

// ---------------------------------------------------------------------------
// W prep: Wt16[l][n][k] = f16(W[l][k][n])
// ---------------------------------------------------------------------------

__global__ __launch_bounds__(256) void k_wprep(const float* __restrict__ Ws, __half* __restrict__ Wt) {
    int l = blockIdx.y;
    int i = blockIdx.x * 256 + threadIdx.x;
    int n = i >> 7, k = i & 127;
    Wt[(size_t)l * DIMM * DIMM + n * DIMM + k] = __float2half(Ws[(size_t)l * DIMM * DIMM + k * DIMM + n]);
}

// ---------------------------------------------------------------------------
// MFMA GEMM: hA(sliced)[s][n][16] = f16( f16(affine(A)) @ f16(W) + b )
// A row-major fp32 (layer 0) or fp16 (later layers).
// ---------------------------------------------------------------------------

__global__ __launch_bounds__(256) void k_gemm(const void* __restrict__ A, const __half* __restrict__ Wt,
                                              const float* __restrict__ bias, const float* __restrict__ ss,
                                              __half* __restrict__ out, int N, int a_half) {
    __shared__ char smem[128 * 272];
    int tid = threadIdx.x;
    int lane = tid & 63, wid = tid >> 6;
    int quad = lane >> 4, lm = lane & 15;
    int row0 = blockIdx.x * 128;

    {
        int seg = tid & 31;
        int col = seg * 4;
        float4 sc = *(const float4*)(ss + col);
        float4 sh = *(const float4*)(ss + 128 + col);
        const float*  Af = (const float*)A;
        const __half* Ah = (const __half*)A;
        for (int i = tid; i < 128 * 32; i += 256) {
            int r = i >> 5;
            int gr = row0 + r;
            float4 v = make_float4(0.f, 0.f, 0.f, 0.f);
            if (gr < N) {
                if (a_half) {
                    union { uint2 u; __half2 h2[2]; } ld;
                    ld.u = *(const uint2*)(Ah + (size_t)gr * DIMM + col);
                    float2 f0 = __half22float2(ld.h2[0]);
                    float2 f1 = __half22float2(ld.h2[1]);
                    v = make_float4(f0.x, f0.y, f1.x, f1.y);
                } else {
                    v = *(const float4*)(Af + (size_t)gr * DIMM + col);
                }
                v.x = v.x * sc.x + sh.x; v.y = v.y * sc.y + sh.y;
                v.z = v.z * sc.z + sh.z; v.w = v.w * sc.w + sh.w;
            }
            union { _Float16 h[4]; uint2 u; } pk;
            pk.h[0] = (_Float16)v.x; pk.h[1] = (_Float16)v.y;
            pk.h[2] = (_Float16)v.z; pk.h[3] = (_Float16)v.w;
            *(uint2*)(smem + r * 272 + seg * 8) = pk.u;
        }
    }

    f32x4 acc[2][8];
    #pragma unroll
    for (int c = 0; c < 8; ++c) {
        float bc = bias[c * 16 + lm];
        acc[0][c] = (f32x4){bc, bc, bc, bc};
        acc[1][c] = acc[0][c];
    }
    __syncthreads();

    const _Float16* Wt16 = (const _Float16*)Wt;
    #pragma unroll
    for (int kc = 0; kc < 4; ++kc) {
        half8 a0 = *(const half8*)(smem + (wid * 32 + lm) * 272 + kc * 64 + quad * 16);
        half8 a1 = *(const half8*)(smem + (wid * 32 + 16 + lm) * 272 + kc * 64 + quad * 16);
        #pragma unroll
        for (int c = 0; c < 8; ++c) {
            half8 b = *(const half8*)(Wt16 + (c * 16 + lm) * DIMM + kc * 32 + quad * 8);
            acc[0][c] = __builtin_amdgcn_mfma_f32_16x16x32_f16(a0, b, acc[0][c], 0, 0, 0);
            acc[1][c] = __builtin_amdgcn_mfma_f32_16x16x32_f16(a1, b, acc[1][c], 0, 0, 0);
        }
    }

    // epilogue: f16 into LDS (row-major 256B rows), then sliced-layout copy out
    __syncthreads();
    #pragma unroll
    for (int r = 0; r < 2; ++r)
        #pragma unroll
        for (int c = 0; c < 8; ++c)
            #pragma unroll
            for (int i = 0; i < 4; ++i) {
                int rit = wid * 32 + r * 16 + quad * 4 + i;
                int col = c * 16 + lm;
                *(_Float16*)(smem + rit * 256 + col * 2) = (_Float16)acc[r][c][i];
            }
    __syncthreads();
    {
        int r = tid & 127, h = tid >> 7;     // h in {0,1}: 16B half of the 32B node-slice
        int gr = row0 + r;
        if (gr < N) {
            #pragma unroll
            for (int s = 0; s < NSLICE; ++s) {
                uivec4 val = *(const uivec4*)(smem + r * 256 + s * 32 + h * 16);
                *(uivec4*)((char*)out + ((size_t)s * N + gr) * 32 + h * 16) = val;
            }
        }
    }
}

// ---------------------------------------------------------------------------
// Aggregate v3 (XCD-sliced walker): slice = blockIdx%8 (16 cols, 3.2MB -> L2
// resident per XCD). Each lane-PAIR owns a node and walks its CSR edges
// sequentially, 4 predicated steps/volley (4 gathers of 16B in flight/lane).
// No cross-lane reduction per node. Self-loop is a csr entry (col==node).
// w recomputed as dinv[col]*dinv[node] (fp32 exact, dinv L2-resident).
// csr loads + hB stores nontemporal (don't evict the slice).
// BN stats per lane (fixed 8 global cols), reduced once at kernel end.
// ---------------------------------------------------------------------------

__device__ __forceinline__ void h8acc(const __half* p, float w, float* v) {
    union { uivec4 u; __half2 h2[4]; } ld;
    ld.u = *(const uivec4*)p;
    #pragma unroll
    for (int q = 0; q < 4; ++q) {
        float2 f = __half22float2(ld.h2[q]);
        v[2 * q]     = fmaf(w, f.x, v[2 * q]);
        v[2 * q + 1] = fmaf(w, f.y, v[2 * q + 1]);
    }
}

__global__ __launch_bounds__(256) void k_agg(const __half* __restrict__ t, __half* __restrict__ out,
                                             const int* __restrict__ rowptr, const int* __restrict__ csr,
                                             const float* __restrict__ dinv,
                                             float* __restrict__ stats, int N, int stride) {
    int tid = threadIdx.x;
    int lane = tid & 63, wid = tid >> 6;
    int pr = lane >> 1;                 // pair 0..31
    int half = lane & 1;                // 8-col half within the 16-col slice
    int s = blockIdx.x & 7;             // slice == XCD (heuristic %8 round-robin)
    int bs = blockIdx.x >> 3;
    int gp = bs * 128 + wid * 32 + pr;  // global pair id within slice

    const __half* ts = t + (size_t)s * N * 16;

    float sx[8] = {0.f,0.f,0.f,0.f,0.f,0.f,0.f,0.f};
    float qx[8] = {0.f,0.f,0.f,0.f,0.f,0.f,0.f,0.f};
    float acc[8] = {0.f,0.f,0.f,0.f,0.f,0.f,0.f,0.f};

    int node = gp;
    int e = 0, eend = 0;
    float dn = 0.f;
    if (node < N) { e = rowptr[node]; eend = rowptr[node + 1]; dn = dinv[node]; }

    for (;;) {
        bool act = (node < N);
        if (__ballot(act) == 0ull) break;
        int e0 = e;
        #pragma unroll
        for (int k = 0; k < 4; ++k) {
            bool st = act && (e0 + k < eend);
            if (st) {
                int col = __builtin_nontemporal_load(csr + e0 + k);
                float w = dinv[col] * dn;
                h8acc(ts + (size_t)col * 16 + half * 8, w, acc);
            }
        }
        if (act) {
            e = min(e0 + 4, eend);
            if (e >= eend) {
                // finalize node: leaky, stats, fp16 store (row-major hB)
                union { _Float16 h[8]; uivec4 u4; } pk;
                #pragma unroll
                for (int i = 0; i < 8; ++i) {
                    float v = acc[i];
                    v = v > 0.f ? v : LEAKY_S * v;
                    sx[i] += v;
                    qx[i] += v * v;
                    pk.h[i] = (_Float16)v;
                    acc[i] = 0.f;
                }
                __builtin_nontemporal_store(pk.u4,
                    (uivec4*)(out + (size_t)node * DIMM + s * 16 + half * 8));
                node += stride;
                if (node < N) { e = rowptr[node]; eend = rowptr[node + 1]; dn = dinv[node]; }
            }
        }
    }

    // reduce stats across the 32 pairs (even shuffles keep half-parity), then block
    #pragma unroll
    for (int i = 0; i < 8; ++i) {
        #pragma unroll
        for (int d = 2; d <= 32; d <<= 1) {
            sx[i] += __shfl_down(sx[i], (unsigned)d, 64);
            qx[i] += __shfl_down(qx[i], (unsigned)d, 64);
        }
    }
    __shared__ float red[4][32];
    if (lane < 2) {
        #pragma unroll
        for (int i = 0; i < 8; ++i) {
            red[wid][half * 8 + i]      = sx[i];
            red[wid][16 + half * 8 + i] = qx[i];
        }
    }
    __syncthreads();
    if (tid < 32) {
        float v = red[0][tid] + red[1][tid] + red[2][tid] + red[3][tid];
        int gc = s * 16 + (tid & 15);
        atomicAdd(&stats[(tid < 16 ? 0 : 128) + gc], v);
    }
}

__global__ __launch_bounds__(128) void k_bnfin(const float* __restrict__ stats, const float* __restrict__ gamma,
                                               const float* __restrict__ beta, float* __restrict__ ss_out,
                                               float inv_n) {
    int c = threadIdx.x;
    float mu  = stats[c] * inv_n;
    float var = stats[128 + c] * inv_n - mu * mu;
    float a = gamma[c] * rsqrtf(var + EPS_BN);
    ss_out[c]       = a;
    ss_out[128 + c] = beta[c] - mu * a;
}

__global__ __launch_bounds__(128) void k_init_ss(float* __restrict__ ss) {
    int c = threadIdx.x;
    ss[c] = 1.0f;
    ss[128 + c] = 0.0f;
}

// ---------------------------------------------------------------------------
// Pooling (hB row-major fp16; pool accum fp32)
// ---------------------------------------------------------------------------

__global__ __launch_bounds__(64) void k_cnt_bs(const int* __restrict__ batch, int* __restrict__ cnt, int N, int G) {
    int g = blockIdx.x * 64 + threadIdx.x;
    if (g >= G) return;
    int lo = 0, hi = N;
    while (lo < hi) { int mid = (lo + hi) >> 1; if (batch[mid] < g) lo = mid + 1; else hi = mid; }
    int lb = lo;
    lo = 0; hi = N;
    while (lo < hi) { int mid = (lo + hi) >> 1; if (batch[mid] <= g) lo = mid + 1; else hi = mid; }
    cnt[g] = lo - lb;
}

__global__ __launch_bounds__(128) void k_pool(const __half* __restrict__ h, const int* __restrict__ batch,
                                              float* __restrict__ pool, int N, int G) {
    const int CHUNK = 128;
    int start = blockIdx.x * CHUNK;
    if (start >= N) return;
    int end = min(start + CHUNK, N);
    int tid = threadIdx.x;
    float acc = 0.f;
    int cur = batch[start];
    for (int n = start; n < end; ++n) {
        int g = batch[n];
        if (g != cur) {
            if ((unsigned)cur < (unsigned)G) atomicAdd(&pool[(size_t)cur * DIMM + tid], acc);
            acc = 0.f; cur = g;
        }
        acc += __half2float(h[(size_t)n * DIMM + tid]);
    }
    if ((unsigned)cur < (unsigned)G) atomicAdd(&pool[(size_t)cur * DIMM + tid], acc);
}

__global__ __launch_bounds__(256) void k_poolfin(const float* __restrict__ pool, const int* __restrict__ cnt,
                                                 const float* __restrict__ ss, float* __restrict__ out, int G) {
    int idx = blockIdx.x * 256 + threadIdx.x;
    if (idx < G * DIMM) {
        int g = idx >> 7, c = idx & 127;
        float m = pool[idx] / (float)max(cnt[g], 1);
        out[idx] = ss[c] * m + ss[128 + c];
    }
}

// ---------------------------------------------------------------------------

extern "C" void kernel_launch(void* const* d_in, const int* in_sizes, int n_in,
                              void* d_out, int out_size, void* d_ws, size_t ws_size,
                              hipStream_t stream) {
    const float* x      = (const float*)d_in[0];
    const int*   ei     = (const int*)d_in[1];
    const int*   batch  = (const int*)d_in[2];
    const float* Ws     = (const float*)d_in[3];
    const float* bs     = (const float*)d_in[4];
    const float* gammas = (const float*)d_in[5];
    const float* betas  = (const float*)d_in[6];
    float* outp = (float*)d_out;

    int N = in_sizes[2];
    int E = in_sizes[1] / 2;
    int L = in_sizes[3] / (DIMM * DIMM);
    int G = out_size / DIMM;

    const int* srcv = ei;
    const int* dstv = ei + E;

    int nb = (N + 1023) / 1024;

    char* w = (char*)d_ws;
    auto alloc = [&](size_t bytes) { char* p = w; w += (bytes + 511) & ~size_t(511); return p; };
    int*    deg    = (int*)   alloc((size_t)N * 4);
    int*    cursor = (int*)   alloc((size_t)N * 4);
    int*    rowptr = (int*)   alloc((size_t)(N + 1) * 4);
    int*    bsum   = (int*)   alloc((size_t)nb * 4);
    int*    bofs   = (int*)   alloc((size_t)nb * 4);
    int*    csrcol = (int*)   alloc((size_t)(E + N) * 4);
    float*  dinv   = (float*) alloc((size_t)N * 4);
    __half* hA     = (__half*)alloc((size_t)N * DIMM * 2);   // sliced layout [8][N][16]
    __half* hB     = (__half*)alloc((size_t)N * DIMM * 2);   // row-major
    __half* Wt     = (__half*)alloc((size_t)L * DIMM * DIMM * 2);
    float*  stats  = (float*) alloc((size_t)L * 256 * 4);
    float*  ss     = (float*) alloc((size_t)(L + 1) * 256 * 4);
    float*  pool   = (float*) alloc((size_t)G * DIMM * 4);
    int*    cnt    = (int*)   alloc((size_t)G * 4);

    (void)hipMemsetAsync(deg,    0, (size_t)N * 4, stream);
    (void)hipMemsetAsync(cursor, 0, (size_t)N * 4, stream);
    (void)hipMemsetAsync(stats,  0, (size_t)L * 256 * 4, stream);
    (void)hipMemsetAsync(pool,   0, (size_t)G * DIMM * 4, stream);

    k_init_ss<<<1, 128, 0, stream>>>(ss);
    k_wprep<<<dim3(64, L), 256, 0, stream>>>(Ws, Wt);
    k_deg  <<<(E + 255) / 256, 256, 0, stream>>>(dstv, deg, E, N);
    k_scanA<<<nb, 256, 0, stream>>>(deg, bsum, N);
    k_scanB<<<1, 64, 0, stream>>>(bsum, bofs, rowptr, nb, N);
    k_scanC<<<nb, 1024, 0, stream>>>(deg, bofs, rowptr, N);
    k_dinvself<<<(N + 255) / 256, 256, 0, stream>>>(deg, rowptr, dinv, csrcol, N);
    k_fill <<<(E + 255) / 256, 256, 0, stream>>>(srcv, dstv, rowptr, cursor, csrcol, E, N);

    const int nblk = 2048;
    const int stride = (nblk / NSLICE) * 128;   // pairs per slice

    const void* cur_in = (const void*)x;
    int a_half = 0;
    for (int l = 0; l < L; ++l) {
        k_gemm<<<(N + 127) / 128, 256, 0, stream>>>(cur_in, Wt + (size_t)l * DIMM * DIMM,
                                                    bs + (size_t)l * DIMM, ss + (size_t)l * 256, hA, N, a_half);
        k_agg<<<nblk, 256, 0, stream>>>(hA, hB, rowptr, csrcol, dinv,
                                        stats + (size_t)l * 256, N, stride);
        k_bnfin<<<1, 128, 0, stream>>>(stats + (size_t)l * 256, gammas + (size_t)l * DIMM,
                                       betas + (size_t)l * DIMM, ss + (size_t)(l + 1) * 256, 1.0f / (float)N);
        cur_in = (const void*)hB;
        a_half = 1;
    }

    k_cnt_bs<<<(G + 63) / 64, 64, 0, stream>>>(batch, cnt, N, G);
    k_pool<<<(N + 127) / 128, 128, 0, stream>>>(hB, batch, pool, N, G);
    k_poolfin<<<(G * DIMM + 255) / 256, 256, 0, stream>>>(pool, cnt, ss + (size_t)L * 256, outp, G);
}

// Round 10
// 1377.952 us; speedup vs baseline: 2.1299x; 2.1299x over previous
//
#include <hip/hip_runtime.h>
#include <hip/hip_fp16.h>

#define DIMM 128
#define LEAKY_S 0.01f
#define EPS_BN 1e-5f

typedef _Float16 half8 __attribute__((ext_vector_type(8)));
typedef float f32x4 __attribute__((ext_vector_type(4)));
typedef unsigned int uivec4 __attribute__((ext_vector_type(4)));

// ---------------------------------------------------------------------------
// Graph preprocessing: degree -> rowptr (scan over deg+1, self-loop slot) ->
// dinv + self entry -> CSR fill (col-only, 4B)
// ---------------------------------------------------------------------------

__global__ __launch_bounds__(256) void k_deg(const int* __restrict__ dst, int* __restrict__ deg, int E, int N) {
    int i = blockIdx.x * 256 + threadIdx.x;
    if (i < E) {
        int d = dst[i];
        if ((unsigned)d < (unsigned)N) atomicAdd(&deg[d], 1);
    }
}

__global__ __launch_bounds__(256) void k_scanA(const int* __restrict__ deg, int* __restrict__ bsum, int n) {
    __shared__ int ws[4];
    int tid = threadIdx.x, lane = tid & 63, wid = tid >> 6;
    int base = blockIdx.x * 1024;
    int s = 0;
    #pragma unroll
    for (int j = 0; j < 4; ++j) {
        int i = base + j * 256 + tid;
        if (i < n) s += deg[i] + 1;          // +1 self-loop slot
    }
    #pragma unroll
    for (int off = 32; off > 0; off >>= 1) s += __shfl_down(s, (unsigned)off, 64);
    if (lane == 0) ws[wid] = s;
    __syncthreads();
    if (tid == 0) bsum[blockIdx.x] = ws[0] + ws[1] + ws[2] + ws[3];
}

__global__ __launch_bounds__(64) void k_scanB(const int* __restrict__ bsum, int* __restrict__ bofs,
                                              int* __restrict__ rowptr, int nb, int n) {
    if (threadIdx.x == 0) {
        int run = 0;
        for (int j = 0; j < nb; ++j) { bofs[j] = run; run += bsum[j]; }
        rowptr[n] = run;
    }
}

__global__ __launch_bounds__(1024) void k_scanC(const int* __restrict__ deg, const int* __restrict__ bofs,
                                                int* __restrict__ rowptr, int n) {
    __shared__ int wsum[16];
    int tid = threadIdx.x, lane = tid & 63, wid = tid >> 6;
    int i = blockIdx.x * 1024 + tid;
    int v = (i < n) ? deg[i] + 1 : 0;        // +1 self-loop slot
    int s = v;
    #pragma unroll
    for (int off = 1; off < 64; off <<= 1) {
        int t = __shfl_up(s, (unsigned)off, 64);
        if (lane >= off) s += t;
    }
    if (lane == 63) wsum[wid] = s;
    __syncthreads();
    if (wid == 0 && lane < 16) {
        int ws = wsum[lane];
        #pragma unroll
        for (int off = 1; off < 16; off <<= 1) {
            int t = __shfl_up(ws, (unsigned)off, 64);
            if (lane >= off) ws += t;
        }
        wsum[lane] = ws;
    }
    __syncthreads();
    int woff = wid ? wsum[wid - 1] : 0;
    if (i < n) rowptr[i] = bofs[blockIdx.x] + woff + (s - v);
}

// dinv + self-loop entry at slot rowptr[i] (col == i)
__global__ __launch_bounds__(256) void k_dinvself(const int* __restrict__ deg, const int* __restrict__ rowptr,
                                                  float* __restrict__ dinv, int* __restrict__ csrcol, int N) {
    int i = blockIdx.x * 256 + threadIdx.x;
    if (i < N) {
        dinv[i] = rsqrtf((float)(deg[i] + 1));
        csrcol[rowptr[i]] = i;
    }
}

// CSR fill: col only (4B). Slot 0 of each row reserved for the self-loop.
__global__ __launch_bounds__(256) void k_fill(const int* __restrict__ src, const int* __restrict__ dst,
                                              const int* __restrict__ rowptr, int* __restrict__ cursor,
                                              int* __restrict__ csrcol, int E, int N) {
    int i = blockIdx.x * 256 + threadIdx.x;
    if (i < E) {
        int d = dst[i], s = src[i];
        if ((unsigned)d < (unsigned)N && (unsigned)s < (unsigned)N) {
            int pos = 1 + atomicAdd(&cursor[d], 1);
            csrcol[rowptr[d] + pos] = s;
        }
    }
}

// ---------------------------------------------------------------------------
// W prep: Wt16[l][n][k] = f16(W[l][k][n])
// ---------------------------------------------------------------------------

__global__ __launch_bounds__(256) void k_wprep(const float* __restrict__ Ws, __half* __restrict__ Wt) {
    int l = blockIdx.y;
    int i = blockIdx.x * 256 + threadIdx.x;
    int n = i >> 7, k = i & 127;
    Wt[(size_t)l * DIMM * DIMM + n * DIMM + k] = __float2half(Ws[(size_t)l * DIMM * DIMM + k * DIMM + n]);
}

// ---------------------------------------------------------------------------
// MFMA GEMM: hA'[N,128] = f16( dinv[row] * (f16(affine(A)) @ f16(W) + b) )
// dinv pre-scaling folds the per-edge GCN weight into the gather operand.
// A row-major fp32 (layer 0) or fp16 (later layers).
// ---------------------------------------------------------------------------

__global__ __launch_bounds__(256) void k_gemm(const void* __restrict__ A, const __half* __restrict__ Wt,
                                              const float* __restrict__ bias, const float* __restrict__ ss,
                                              const float* __restrict__ dinv,
                                              __half* __restrict__ out, int N, int a_half) {
    __shared__ char smem[128 * 272];   // staging (272B rows) / epilogue (256B rows)
    int tid = threadIdx.x;
    int lane = tid & 63, wid = tid >> 6;
    int quad = lane >> 4, lm = lane & 15;
    int row0 = blockIdx.x * 128;

    {
        int seg = tid & 31;
        int col = seg * 4;
        float4 sc = *(const float4*)(ss + col);
        float4 sh = *(const float4*)(ss + 128 + col);
        const float*  Af = (const float*)A;
        const __half* Ah = (const __half*)A;
        for (int i = tid; i < 128 * 32; i += 256) {
            int r = i >> 5;
            int gr = row0 + r;
            float4 v = make_float4(0.f, 0.f, 0.f, 0.f);
            if (gr < N) {
                if (a_half) {
                    union { uint2 u; __half2 h2[2]; } ld;
                    ld.u = *(const uint2*)(Ah + (size_t)gr * DIMM + col);
                    float2 f0 = __half22float2(ld.h2[0]);
                    float2 f1 = __half22float2(ld.h2[1]);
                    v = make_float4(f0.x, f0.y, f1.x, f1.y);
                } else {
                    v = *(const float4*)(Af + (size_t)gr * DIMM + col);
                }
                v.x = v.x * sc.x + sh.x; v.y = v.y * sc.y + sh.y;
                v.z = v.z * sc.z + sh.z; v.w = v.w * sc.w + sh.w;
            }
            union { _Float16 h[4]; uint2 u; } pk;
            pk.h[0] = (_Float16)v.x; pk.h[1] = (_Float16)v.y;
            pk.h[2] = (_Float16)v.z; pk.h[3] = (_Float16)v.w;
            *(uint2*)(smem + r * 272 + seg * 8) = pk.u;
        }
    }

    f32x4 acc[2][8];
    #pragma unroll
    for (int c = 0; c < 8; ++c) {
        float bc = bias[c * 16 + lm];
        acc[0][c] = (f32x4){bc, bc, bc, bc};
        acc[1][c] = acc[0][c];
    }
    __syncthreads();

    const _Float16* Wt16 = (const _Float16*)Wt;
    #pragma unroll
    for (int kc = 0; kc < 4; ++kc) {
        half8 a0 = *(const half8*)(smem + (wid * 32 + lm) * 272 + kc * 64 + quad * 16);
        half8 a1 = *(const half8*)(smem + (wid * 32 + 16 + lm) * 272 + kc * 64 + quad * 16);
        #pragma unroll
        for (int c = 0; c < 8; ++c) {
            half8 b = *(const half8*)(Wt16 + (c * 16 + lm) * DIMM + kc * 32 + quad * 8);
            acc[0][c] = __builtin_amdgcn_mfma_f32_16x16x32_f16(a0, b, acc[0][c], 0, 0, 0);
            acc[1][c] = __builtin_amdgcn_mfma_f32_16x16x32_f16(a1, b, acc[1][c], 0, 0, 0);
        }
    }

    // per-row dinv for this thread's 8 accumulator rows (broadcast across lm)
    float dv[2][4];
    #pragma unroll
    for (int r = 0; r < 2; ++r)
        #pragma unroll
        for (int i = 0; i < 4; ++i) {
            int gr = row0 + wid * 32 + r * 16 + quad * 4 + i;
            dv[r][i] = (gr < N) ? dinv[gr] : 0.f;
        }

    // epilogue: scale by dinv, f16 into LDS (256B rows), coalesced row-major copy
    __syncthreads();
    #pragma unroll
    for (int r = 0; r < 2; ++r)
        #pragma unroll
        for (int c = 0; c < 8; ++c)
            #pragma unroll
            for (int i = 0; i < 4; ++i) {
                int rit = wid * 32 + r * 16 + quad * 4 + i;
                int col = c * 16 + lm;
                *(_Float16*)(smem + rit * 256 + col * 2) = (_Float16)(acc[r][c][i] * dv[r][i]);
            }
    __syncthreads();
    for (int i = tid; i < 128 * 16; i += 256) {
        int r = i >> 4, seg = i & 15;
        int gr = row0 + r;
        if (gr < N)
            ((uivec4*)(out + (size_t)gr * DIMM))[seg] = ((const uivec4*)(smem + r * 256))[seg];
    }
}

// ---------------------------------------------------------------------------
// Aggregate (weightless gather): wave per node (strided); 4 edge-groups x
// 16 lanes; lane loads 16B = 8 cols / edge of the dinv-pre-scaled operand.
// out[n] = leaky( dinv[n] * sum_e hA'[col_e] )   (self-loop is a csr entry)
// Per edge: one 4B col load + one 16B gather + 8 adds. BN stats fused.
// ---------------------------------------------------------------------------

__device__ __forceinline__ void h8add(const __half* p, float* v) {
    union { uivec4 u; __half2 h2[4]; } ld;
    ld.u = *(const uivec4*)p;
    #pragma unroll
    for (int q = 0; q < 4; ++q) {
        float2 f = __half22float2(ld.h2[q]);
        v[2 * q]     += f.x;
        v[2 * q + 1] += f.y;
    }
}

__global__ __launch_bounds__(256) void k_agg(const __half* __restrict__ t, __half* __restrict__ out,
                                             const int* __restrict__ rowptr, const int* __restrict__ csr,
                                             const float* __restrict__ dinv,
                                             float* __restrict__ stats, int N, int nwaves) {
    int tid = threadIdx.x;
    int lane = tid & 63, wid = tid >> 6;
    int grp = lane >> 4;       // edge group 0..3
    int l16 = lane & 15;       // covers cols [8*l16, 8*l16+8)
    int gw = blockIdx.x * 4 + wid;

    float sx[8] = {0.f,0.f,0.f,0.f,0.f,0.f,0.f,0.f};
    float qx[8] = {0.f,0.f,0.f,0.f,0.f,0.f,0.f,0.f};

    for (int node = gw; node < N; node += nwaves) {
        float dn = dinv[node];
        float v[8] = {0.f,0.f,0.f,0.f,0.f,0.f,0.f,0.f};
        int e = rowptr[node], e1 = rowptr[node + 1];
        // main: exact 16-edge blocks, unpredicated
        for (; e + 16 <= e1; e += 16) {
            #pragma unroll
            for (int j = 0; j < 4; ++j) {
                int col = __builtin_nontemporal_load(csr + e + 4 * j + grp);
                h8add(t + (size_t)col * DIMM + l16 * 8, v);
            }
        }
        // remainder: up to 15 edges, predicated
        if (e < e1) {
            #pragma unroll
            for (int j = 0; j < 4; ++j) {
                int idx = e + 4 * j + grp;
                if (idx < e1) {
                    int col = __builtin_nontemporal_load(csr + idx);
                    h8add(t + (size_t)col * DIMM + l16 * 8, v);
                }
            }
        }
        // combine the 4 group partials
        #pragma unroll
        for (int i = 0; i < 8; ++i) {
            v[i] += __shfl_down(v[i], 32, 64);
            v[i] += __shfl_down(v[i], 16, 64);
        }
        if (grp == 0) {
            union { _Float16 h[8]; uivec4 u4; } pk;
            #pragma unroll
            for (int i = 0; i < 8; ++i) {
                float w = dn * v[i];
                w = w > 0.f ? w : LEAKY_S * w;
                sx[i] += w;
                qx[i] += w * w;
                pk.h[i] = (_Float16)w;
            }
            *(uivec4*)(out + (size_t)node * DIMM + l16 * 8) = pk.u4;
        }
    }

    __shared__ float red[4 * 128];
    if (grp == 0) {
        *(float4*)(red + wid * 128 + l16 * 8)     = make_float4(sx[0], sx[1], sx[2], sx[3]);
        *(float4*)(red + wid * 128 + l16 * 8 + 4) = make_float4(sx[4], sx[5], sx[6], sx[7]);
    }
    __syncthreads();
    if (tid < 128) {
        float s = red[tid] + red[128 + tid] + red[256 + tid] + red[384 + tid];
        atomicAdd(&stats[tid], s);
    }
    __syncthreads();
    if (grp == 0) {
        *(float4*)(red + wid * 128 + l16 * 8)     = make_float4(qx[0], qx[1], qx[2], qx[3]);
        *(float4*)(red + wid * 128 + l16 * 8 + 4) = make_float4(qx[4], qx[5], qx[6], qx[7]);
    }
    __syncthreads();
    if (tid < 128) {
        float s = red[tid] + red[128 + tid] + red[256 + tid] + red[384 + tid];
        atomicAdd(&stats[128 + tid], s);
    }
}

__global__ __launch_bounds__(128) void k_bnfin(const float* __restrict__ stats, const float* __restrict__ gamma,
                                               const float* __restrict__ beta, float* __restrict__ ss_out,
                                               float inv_n) {
    int c = threadIdx.x;
    float mu  = stats[c] * inv_n;
    float var = stats[128 + c] * inv_n - mu * mu;
    float a = gamma[c] * rsqrtf(var + EPS_BN);
    ss_out[c]       = a;
    ss_out[128 + c] = beta[c] - mu * a;
}

__global__ __launch_bounds__(128) void k_init_ss(float* __restrict__ ss) {
    int c = threadIdx.x;
    ss[c] = 1.0f;
    ss[128 + c] = 0.0f;
}

// ---------------------------------------------------------------------------
// Pooling (hB row-major fp16; pool accum fp32)
// ---------------------------------------------------------------------------

__global__ __launch_bounds__(64) void k_cnt_bs(const int* __restrict__ batch, int* __restrict__ cnt, int N, int G) {
    int g = blockIdx.x * 64 + threadIdx.x;
    if (g >= G) return;
    int lo = 0, hi = N;
    while (lo < hi) { int mid = (lo + hi) >> 1; if (batch[mid] < g) lo = mid + 1; else hi = mid; }
    int lb = lo;
    lo = 0; hi = N;
    while (lo < hi) { int mid = (lo + hi) >> 1; if (batch[mid] <= g) lo = mid + 1; else hi = mid; }
    cnt[g] = lo - lb;
}

__global__ __launch_bounds__(128) void k_pool(const __half* __restrict__ h, const int* __restrict__ batch,
                                              float* __restrict__ pool, int N, int G) {
    const int CHUNK = 128;
    int start = blockIdx.x * CHUNK;
    if (start >= N) return;
    int end = min(start + CHUNK, N);
    int tid = threadIdx.x;
    float acc = 0.f;
    int cur = batch[start];
    for (int n = start; n < end; ++n) {
        int g = batch[n];
        if (g != cur) {
            if ((unsigned)cur < (unsigned)G) atomicAdd(&pool[(size_t)cur * DIMM + tid], acc);
            acc = 0.f; cur = g;
        }
        acc += __half2float(h[(size_t)n * DIMM + tid]);
    }
    if ((unsigned)cur < (unsigned)G) atomicAdd(&pool[(size_t)cur * DIMM + tid], acc);
}

__global__ __launch_bounds__(256) void k_poolfin(const float* __restrict__ pool, const int* __restrict__ cnt,
                                                 const float* __restrict__ ss, float* __restrict__ out, int G) {
    int idx = blockIdx.x * 256 + threadIdx.x;
    if (idx < G * DIMM) {
        int g = idx >> 7, c = idx & 127;
        float m = pool[idx] / (float)max(cnt[g], 1);
        out[idx] = ss[c] * m + ss[128 + c];
    }
}

// ---------------------------------------------------------------------------

extern "C" void kernel_launch(void* const* d_in, const int* in_sizes, int n_in,
                              void* d_out, int out_size, void* d_ws, size_t ws_size,
                              hipStream_t stream) {
    const float* x      = (const float*)d_in[0];
    const int*   ei     = (const int*)d_in[1];
    const int*   batch  = (const int*)d_in[2];
    const float* Ws     = (const float*)d_in[3];
    const float* bs     = (const float*)d_in[4];
    const float* gammas = (const float*)d_in[5];
    const float* betas  = (const float*)d_in[6];
    float* outp = (float*)d_out;

    int N = in_sizes[2];
    int E = in_sizes[1] / 2;
    int L = in_sizes[3] / (DIMM * DIMM);
    int G = out_size / DIMM;

    const int* srcv = ei;
    const int* dstv = ei + E;

    int nb = (N + 1023) / 1024;

    char* w = (char*)d_ws;
    auto alloc = [&](size_t bytes) { char* p = w; w += (bytes + 511) & ~size_t(511); return p; };
    int*    deg    = (int*)   alloc((size_t)N * 4);
    int*    cursor = (int*)   alloc((size_t)N * 4);
    int*    rowptr = (int*)   alloc((size_t)(N + 1) * 4);
    int*    bsum   = (int*)   alloc((size_t)nb * 4);
    int*    bofs   = (int*)   alloc((size_t)nb * 4);
    int*    csrcol = (int*)   alloc((size_t)(E + N) * 4);
    float*  dinv   = (float*) alloc((size_t)N * 4);
    __half* hA     = (__half*)alloc((size_t)N * DIMM * 2);   // row-major, dinv-pre-scaled
    __half* hB     = (__half*)alloc((size_t)N * DIMM * 2);   // row-major
    __half* Wt     = (__half*)alloc((size_t)L * DIMM * DIMM * 2);
    float*  stats  = (float*) alloc((size_t)L * 256 * 4);
    float*  ss     = (float*) alloc((size_t)(L + 1) * 256 * 4);
    float*  pool   = (float*) alloc((size_t)G * DIMM * 4);
    int*    cnt    = (int*)   alloc((size_t)G * 4);

    (void)hipMemsetAsync(deg,    0, (size_t)N * 4, stream);
    (void)hipMemsetAsync(cursor, 0, (size_t)N * 4, stream);
    (void)hipMemsetAsync(stats,  0, (size_t)L * 256 * 4, stream);
    (void)hipMemsetAsync(pool,   0, (size_t)G * DIMM * 4, stream);

    k_init_ss<<<1, 128, 0, stream>>>(ss);
    k_wprep<<<dim3(64, L), 256, 0, stream>>>(Ws, Wt);
    k_deg  <<<(E + 255) / 256, 256, 0, stream>>>(dstv, deg, E, N);
    k_scanA<<<nb, 256, 0, stream>>>(deg, bsum, N);
    k_scanB<<<1, 64, 0, stream>>>(bsum, bofs, rowptr, nb, N);
    k_scanC<<<nb, 1024, 0, stream>>>(deg, bofs, rowptr, N);
    k_dinvself<<<(N + 255) / 256, 256, 0, stream>>>(deg, rowptr, dinv, csrcol, N);
    k_fill <<<(E + 255) / 256, 256, 0, stream>>>(srcv, dstv, rowptr, cursor, csrcol, E, N);

    const void* cur_in = (const void*)x;
    int a_half = 0;
    for (int l = 0; l < L; ++l) {
        k_gemm<<<(N + 127) / 128, 256, 0, stream>>>(cur_in, Wt + (size_t)l * DIMM * DIMM,
                                                    bs + (size_t)l * DIMM, ss + (size_t)l * 256,
                                                    dinv, hA, N, a_half);
        const int nblk = 2048;   // 8192 waves, strided node assignment
        k_agg<<<nblk, 256, 0, stream>>>(hA, hB, rowptr, csrcol, dinv,
                                        stats + (size_t)l * 256, N, nblk * 4);
        k_bnfin<<<1, 128, 0, stream>>>(stats + (size_t)l * 256, gammas + (size_t)l * DIMM,
                                       betas + (size_t)l * DIMM, ss + (size_t)(l + 1) * 256, 1.0f / (float)N);
        cur_in = (const void*)hB;
        a_half = 1;
    }

    k_cnt_bs<<<(G + 63) / 64, 64, 0, stream>>>(batch, cnt, N, G);
    k_pool<<<(N + 127) / 128, 128, 0, stream>>>(hB, batch, pool, N, G);
    k_poolfin<<<(G * DIMM + 255) / 256, 256, 0, stream>>>(pool, cnt, ss + (size_t)L * 256, outp, G);
}